// Round 1
// baseline (6313.330 us; speedup 1.0000x reference)
//
#include <hip/hip_runtime.h>

#define IN_DIM 256
#define HID 256

// ---------------- degree ----------------
__global__ void k_count_deg(const int* __restrict__ dst, float* __restrict__ deg, int E) {
    int e = blockIdx.x * blockDim.x + threadIdx.x;
    if (e < E) atomicAdd(&deg[dst[e]], 1.0f);
}

__global__ void k_recip(float* __restrict__ deg, int n) {
    int i = blockIdx.x * blockDim.x + threadIdx.x;
    if (i < n) deg[i] = 1.0f / fmaxf(deg[i], 1.0f);
}

// ---------------- scatter-add: agg[dst] += X[src]; one wave (64 lanes) per edge ----------------
__global__ __launch_bounds__(256) void k_scatter(const float* __restrict__ X,
                                                 const int* __restrict__ src,
                                                 const int* __restrict__ dst,
                                                 float* __restrict__ agg, int E) {
    int lane = threadIdx.x & 63;
    int edge = blockIdx.x * 4 + (threadIdx.x >> 6);
    if (edge >= E) return;
    int s = src[edge], d = dst[edge];
    float4 v = ((const float4*)(X + (size_t)s * HID))[lane];
    float* a = agg + (size_t)d * HID + lane * 4;
    atomicAdd(a + 0, v.x);
    atomicAdd(a + 1, v.y);
    atomicAdd(a + 2, v.z);
    atomicAdd(a + 3, v.w);
}

// ---------------- fused GEMM: C = act( rowscaleA*A @ Wa + B @ Wb + bias ) ----------------
// A:[M,Ka] B:[M,Kb] Wa:[Ka,N] Wb:[Kb,N] all row-major. 64x64 tile, 256 thr, 4x4 microtile.
#define GM 64
#define GN 64
#define GK 16

__global__ __launch_bounds__(256) void k_gemm(
    const float* __restrict__ A, const float* __restrict__ Wa, int Ka,
    const float* __restrict__ B, const float* __restrict__ Wb, int Kb,
    const float* __restrict__ rowscaleA,
    const float* __restrict__ bias, int relu,
    float* __restrict__ C, int M, int N)
{
    __shared__ float As[GK][GM + 1];
    __shared__ float Ws[GK][GN + 4];
    const int tid = threadIdx.x;
    const int m0 = blockIdx.y * GM;
    const int n0 = blockIdx.x * GN;
    const int tx = tid & 15;        // n-sub
    const int ty = tid >> 4;        // m-sub
    // A-load mapping: one float4 per thread: row 0..63, k-quad 0..3
    const int lrow = tid >> 2, lkq = tid & 3;
    int arow = m0 + lrow; if (arow >= M) arow = M - 1;
    const float ascale = rowscaleA ? rowscaleA[arow] : 1.0f;
    // W-load mapping: k-row 0..15, n-quad 0..15
    const int wk = tid >> 4, wn = (tid & 15) * 4;

    float acc[4][4] = {};

    for (int pass = 0; pass < 2; ++pass) {
        const float* Ap = (pass == 0) ? A : B;
        const float* Wp = (pass == 0) ? Wa : Wb;
        const int K = (pass == 0) ? Ka : Kb;
        const float sc = (pass == 0) ? ascale : 1.0f;
        if (Ap == nullptr || K == 0) continue;
        for (int k0 = 0; k0 < K; k0 += GK) {
            __syncthreads();
            float4 av = *(const float4*)(Ap + (size_t)arow * K + k0 + lkq * 4);
            float4 wv = *(const float4*)(Wp + (size_t)(k0 + wk) * N + n0 + wn);
            As[lkq * 4 + 0][lrow] = av.x * sc;
            As[lkq * 4 + 1][lrow] = av.y * sc;
            As[lkq * 4 + 2][lrow] = av.z * sc;
            As[lkq * 4 + 3][lrow] = av.w * sc;
            *(float4*)&Ws[wk][wn] = wv;
            __syncthreads();
#pragma unroll
            for (int k = 0; k < GK; ++k) {
                float a[4], b[4];
#pragma unroll
                for (int i = 0; i < 4; ++i) a[i] = As[k][ty * 4 + i];
#pragma unroll
                for (int j = 0; j < 4; ++j) b[j] = Ws[k][tx * 4 + j];
#pragma unroll
                for (int i = 0; i < 4; ++i)
#pragma unroll
                    for (int j = 0; j < 4; ++j)
                        acc[i][j] += a[i] * b[j];
            }
        }
    }

    float4 bv = make_float4(0.f, 0.f, 0.f, 0.f);
    if (bias) bv = ((const float4*)bias)[(n0 >> 2) + tx];
#pragma unroll
    for (int i = 0; i < 4; ++i) {
        int m = m0 + ty * 4 + i;
        if (m >= M) continue;
        float4 v;
        v.x = acc[i][0] + bv.x;
        v.y = acc[i][1] + bv.y;
        v.z = acc[i][2] + bv.z;
        v.w = acc[i][3] + bv.w;
        if (relu) {
            v.x = fmaxf(v.x, 0.f); v.y = fmaxf(v.y, 0.f);
            v.z = fmaxf(v.z, 0.f); v.w = fmaxf(v.w, 0.f);
        }
        *(float4*)(C + (size_t)m * N + n0 + tx * 4) = v;
    }
}

// ---------------- edge MLP: logits[e] = relu(P[src]+Q[dst]+bm1) @ Wm2 + bm2 ----------------
// one wave per edge; lane handles 4 channels
__global__ __launch_bounds__(256) void k_edge(const float* __restrict__ P,
                                              const float* __restrict__ Q,
                                              const int* __restrict__ src,
                                              const int* __restrict__ dst,
                                              const float* __restrict__ bm1,
                                              const float* __restrict__ Wm2,
                                              const float* __restrict__ bm2,
                                              float* __restrict__ out, int E) {
    int lane = threadIdx.x & 63;
    int edge = blockIdx.x * 4 + (threadIdx.x >> 6);
    if (edge >= E) return;
    int s = src[edge], d = dst[edge];
    float4 p = ((const float4*)(P + (size_t)s * HID))[lane];
    float4 q = ((const float4*)(Q + (size_t)d * HID))[lane];
    float4 b = ((const float4*)bm1)[lane];
    float4 h;
    h.x = fmaxf(p.x + q.x + b.x, 0.f);
    h.y = fmaxf(p.y + q.y + b.y, 0.f);
    h.z = fmaxf(p.z + q.z + b.z, 0.f);
    h.w = fmaxf(p.w + q.w + b.w, 0.f);
    // Wm2 [256,2] row-major; this lane's 4 rows = float4s at 2*lane, 2*lane+1
    float4 w01 = ((const float4*)Wm2)[lane * 2];
    float4 w23 = ((const float4*)Wm2)[lane * 2 + 1];
    float a0 = h.x * w01.x + h.y * w01.z + h.z * w23.x + h.w * w23.z;
    float a1 = h.x * w01.y + h.y * w01.w + h.z * w23.y + h.w * w23.w;
#pragma unroll
    for (int off = 32; off > 0; off >>= 1) {
        a0 += __shfl_down(a0, off, 64);
        a1 += __shfl_down(a1, off, 64);
    }
    if (lane == 0) {
        float2 o;
        o.x = a0 + bm2[0];
        o.y = a1 + bm2[1];
        ((float2*)out)[edge] = o;
    }
}

extern "C" void kernel_launch(void* const* d_in, const int* in_sizes, int n_in,
                              void* d_out, int out_size, void* d_ws, size_t ws_size,
                              hipStream_t stream) {
    const float* x   = (const float*)d_in[0];
    const int*   ei  = (const int*)d_in[1];
    const float* W1l = (const float*)d_in[2];
    const float* b1l = (const float*)d_in[3];
    const float* W1r = (const float*)d_in[4];
    const float* W2l = (const float*)d_in[5];
    const float* b2l = (const float*)d_in[6];
    const float* W2r = (const float*)d_in[7];
    const float* Wm1 = (const float*)d_in[8];
    const float* bm1 = (const float*)d_in[9];
    const float* Wm2 = (const float*)d_in[10];
    const float* bm2 = (const float*)d_in[11];

    const int N = in_sizes[0] / IN_DIM;   // 50000
    const int E = in_sizes[1] / 2;        // 800000
    const int* src = ei;
    const int* dst = ei + E;

    char* ws = (char*)d_ws;
    float* deg = (float*)ws;                                  // N floats (becomes inv_deg)
    size_t degB = (((size_t)N * 4) + 255) & ~(size_t)255;
    size_t matB = (size_t)N * HID * sizeof(float);            // 51.2 MB
    float* bufA = (float*)(ws + degB);
    float* bufB = (float*)(ws + degB + matB);
    float* bufC = (float*)(ws + degB + 2 * matB);
    float* out = (float*)d_out;

    dim3 gg(HID / GN, (N + GM - 1) / GM);
    int ewg = (E + 3) / 4;

    // degrees (shared by both convs)
    hipMemsetAsync(deg, 0, (size_t)N * 4, stream);
    k_count_deg<<<(E + 255) / 256, 256, 0, stream>>>(dst, deg, E);
    k_recip<<<(N + 255) / 256, 256, 0, stream>>>(deg, N);

    // conv1: agg -> bufA ; h1 -> bufB
    hipMemsetAsync(bufA, 0, matB, stream);
    k_scatter<<<ewg, 256, 0, stream>>>(x, src, dst, bufA, E);
    k_gemm<<<gg, 256, 0, stream>>>(bufA, W1l, IN_DIM, x, W1r, IN_DIM, deg, b1l, 1, bufB, N, HID);

    // conv2: agg -> bufA (reuse) ; h2 -> bufC
    hipMemsetAsync(bufA, 0, matB, stream);
    k_scatter<<<ewg, 256, 0, stream>>>(bufB, src, dst, bufA, E);
    k_gemm<<<gg, 256, 0, stream>>>(bufA, W2l, HID, bufB, W2r, HID, deg, b2l, 1, bufC, N, HID);

    // P = h2 @ Wm1[:256]  -> bufA ; Q = h2 @ Wm1[256:] -> bufB
    k_gemm<<<gg, 256, 0, stream>>>(bufC, Wm1, HID, nullptr, nullptr, 0, nullptr, nullptr, 0, bufA, N, HID);
    k_gemm<<<gg, 256, 0, stream>>>(bufC, Wm1 + (size_t)HID * HID, HID, nullptr, nullptr, 0, nullptr, nullptr, 0, bufB, N, HID);

    // edge MLP -> logits
    k_edge<<<ewg, 256, 0, stream>>>(bufA, bufB, src, dst, bm1, Wm2, bm2, out, E);
}

// Round 2
// 1187.108 us; speedup vs baseline: 5.3182x; 5.3182x over previous
//
#include <hip/hip_runtime.h>

#define IN_DIM 256
#define HID 256
#define SCAN_CHUNK 512

// ---------------- degree (int) ----------------
__global__ void k_count_deg(const int* __restrict__ dst, int* __restrict__ deg, int E) {
    int e = blockIdx.x * blockDim.x + threadIdx.x;
    if (e < E) atomicAdd(&deg[dst[e]], 1);
}

// ---------------- scan step 1: per-chunk sums ----------------
__global__ __launch_bounds__(64) void k_chunk_sum(const int* __restrict__ deg,
                                                  int* __restrict__ partials, int N) {
    int lane = threadIdx.x;
    int base = blockIdx.x * SCAN_CHUNK + lane * 8;
    int s = 0;
#pragma unroll
    for (int i = 0; i < 8; ++i) s += (base + i < N) ? deg[base + i] : 0;
#pragma unroll
    for (int off = 32; off > 0; off >>= 1) s += __shfl_down(s, off, 64);
    if (lane == 0) partials[blockIdx.x] = s;
}

// ---------------- scan step 2: exclusive scan of partials (tiny) ----------------
__global__ void k_scan_partials(int* __restrict__ partials, int nb) {
    if (threadIdx.x == 0 && blockIdx.x == 0) {
        int run = 0;
        for (int i = 0; i < nb; ++i) { int v = partials[i]; partials[i] = run; run += v; }
    }
}

// ---------------- scan step 3: per-chunk exclusive scan -> row_start, cursor ----------------
__global__ __launch_bounds__(64) void k_scan_chunks(const int* __restrict__ deg,
                                                    const int* __restrict__ partials,
                                                    int* __restrict__ row_start,
                                                    int* __restrict__ cursor, int N) {
    int lane = threadIdx.x;
    int base = blockIdx.x * SCAN_CHUNK + lane * 8;
    int v[8]; int lsum = 0;
#pragma unroll
    for (int i = 0; i < 8; ++i) { v[i] = (base + i < N) ? deg[base + i] : 0; lsum += v[i]; }
    int pre = lsum;
#pragma unroll
    for (int off = 1; off < 64; off <<= 1) {
        int t = __shfl_up(pre, off, 64);
        if (lane >= off) pre += t;
    }
    pre -= lsum;  // exclusive
    int run = partials[blockIdx.x] + pre;
#pragma unroll
    for (int i = 0; i < 8; ++i) {
        if (base + i < N) { row_start[base + i] = run; cursor[base + i] = run; }
        run += v[i];
    }
}

// ---------------- bucket fill: csr_src[pos] = src[e] grouped by dst ----------------
__global__ void k_bucket(const int* __restrict__ src, const int* __restrict__ dst,
                         int* __restrict__ cursor, int* __restrict__ csr_src, int E) {
    int e = blockIdx.x * blockDim.x + threadIdx.x;
    if (e < E) {
        int pos = atomicAdd(&cursor[dst[e]], 1);
        csr_src[pos] = src[e];
    }
}

// ---------------- gather-aggregate: agg[v] = mean_{s in N(v)} X[s]; one wave/node ----------------
__global__ __launch_bounds__(256) void k_gather(const float* __restrict__ X,
                                                const int* __restrict__ csr_src,
                                                const int* __restrict__ row_start,
                                                const int* __restrict__ deg,
                                                float* __restrict__ agg, int N) {
    int lane = threadIdx.x & 63;
    int node = blockIdx.x * 4 + (threadIdx.x >> 6);
    if (node >= N) return;
    int start = row_start[node];
    int cnt = deg[node];
    const int* sp = csr_src + start;
    float ax = 0.f, ay = 0.f, az = 0.f, aw = 0.f;
    int j = 0;
    for (; j + 2 <= cnt; j += 2) {
        int s0 = sp[j], s1 = sp[j + 1];
        float4 a = ((const float4*)(X + (size_t)s0 * HID))[lane];
        float4 b = ((const float4*)(X + (size_t)s1 * HID))[lane];
        ax += a.x + b.x; ay += a.y + b.y; az += a.z + b.z; aw += a.w + b.w;
    }
    if (j < cnt) {
        float4 a = ((const float4*)(X + (size_t)sp[j] * HID))[lane];
        ax += a.x; ay += a.y; az += a.z; aw += a.w;
    }
    float sc = 1.0f / (float)max(cnt, 1);
    float4 o; o.x = ax * sc; o.y = ay * sc; o.z = az * sc; o.w = aw * sc;
    ((float4*)(agg + (size_t)node * HID))[lane] = o;
}

// ---------------- fused GEMM: C = act( A @ Wa + B @ Wb + bias ) ----------------
#define GM 64
#define GN 64
#define GK 16

__global__ __launch_bounds__(256) void k_gemm(
    const float* __restrict__ A, const float* __restrict__ Wa, int Ka,
    const float* __restrict__ B, const float* __restrict__ Wb, int Kb,
    const float* __restrict__ bias, int relu,
    float* __restrict__ C, int M, int N)
{
    __shared__ float As[GK][GM + 1];
    __shared__ float Ws[GK][GN + 4];
    const int tid = threadIdx.x;
    const int m0 = blockIdx.y * GM;
    const int n0 = blockIdx.x * GN;
    const int tx = tid & 15;
    const int ty = tid >> 4;
    const int lrow = tid >> 2, lkq = tid & 3;
    int arow = m0 + lrow; if (arow >= M) arow = M - 1;
    const int wk = tid >> 4, wn = (tid & 15) * 4;

    float acc[4][4] = {};

    for (int pass = 0; pass < 2; ++pass) {
        const float* Ap = (pass == 0) ? A : B;
        const float* Wp = (pass == 0) ? Wa : Wb;
        const int K = (pass == 0) ? Ka : Kb;
        if (Ap == nullptr || K == 0) continue;
        for (int k0 = 0; k0 < K; k0 += GK) {
            __syncthreads();
            float4 av = *(const float4*)(Ap + (size_t)arow * K + k0 + lkq * 4);
            float4 wv = *(const float4*)(Wp + (size_t)(k0 + wk) * N + n0 + wn);
            As[lkq * 4 + 0][lrow] = av.x;
            As[lkq * 4 + 1][lrow] = av.y;
            As[lkq * 4 + 2][lrow] = av.z;
            As[lkq * 4 + 3][lrow] = av.w;
            *(float4*)&Ws[wk][wn] = wv;
            __syncthreads();
#pragma unroll
            for (int k = 0; k < GK; ++k) {
                float a[4], b[4];
#pragma unroll
                for (int i = 0; i < 4; ++i) a[i] = As[k][ty * 4 + i];
#pragma unroll
                for (int j = 0; j < 4; ++j) b[j] = Ws[k][tx * 4 + j];
#pragma unroll
                for (int i = 0; i < 4; ++i)
#pragma unroll
                    for (int j = 0; j < 4; ++j)
                        acc[i][j] += a[i] * b[j];
            }
        }
    }

    float4 bv = make_float4(0.f, 0.f, 0.f, 0.f);
    if (bias) bv = ((const float4*)bias)[(n0 >> 2) + tx];
#pragma unroll
    for (int i = 0; i < 4; ++i) {
        int m = m0 + ty * 4 + i;
        if (m >= M) continue;
        float4 v;
        v.x = acc[i][0] + bv.x;
        v.y = acc[i][1] + bv.y;
        v.z = acc[i][2] + bv.z;
        v.w = acc[i][3] + bv.w;
        if (relu) {
            v.x = fmaxf(v.x, 0.f); v.y = fmaxf(v.y, 0.f);
            v.z = fmaxf(v.z, 0.f); v.w = fmaxf(v.w, 0.f);
        }
        *(float4*)(C + (size_t)m * N + n0 + tx * 4) = v;
    }
}

// ---------------- edge MLP: logits[e] = relu(P[src]+Q[dst]+bm1) @ Wm2 + bm2 ----------------
__global__ __launch_bounds__(256) void k_edge(const float* __restrict__ P,
                                              const float* __restrict__ Q,
                                              const int* __restrict__ src,
                                              const int* __restrict__ dst,
                                              const float* __restrict__ bm1,
                                              const float* __restrict__ Wm2,
                                              const float* __restrict__ bm2,
                                              float* __restrict__ out, int E) {
    int lane = threadIdx.x & 63;
    int edge = blockIdx.x * 4 + (threadIdx.x >> 6);
    if (edge >= E) return;
    int s = src[edge], d = dst[edge];
    float4 p = ((const float4*)(P + (size_t)s * HID))[lane];
    float4 q = ((const float4*)(Q + (size_t)d * HID))[lane];
    float4 b = ((const float4*)bm1)[lane];
    float4 h;
    h.x = fmaxf(p.x + q.x + b.x, 0.f);
    h.y = fmaxf(p.y + q.y + b.y, 0.f);
    h.z = fmaxf(p.z + q.z + b.z, 0.f);
    h.w = fmaxf(p.w + q.w + b.w, 0.f);
    float4 w01 = ((const float4*)Wm2)[lane * 2];
    float4 w23 = ((const float4*)Wm2)[lane * 2 + 1];
    float a0 = h.x * w01.x + h.y * w01.z + h.z * w23.x + h.w * w23.z;
    float a1 = h.x * w01.y + h.y * w01.w + h.z * w23.y + h.w * w23.w;
#pragma unroll
    for (int off = 32; off > 0; off >>= 1) {
        a0 += __shfl_down(a0, off, 64);
        a1 += __shfl_down(a1, off, 64);
    }
    if (lane == 0) {
        float2 o;
        o.x = a0 + bm2[0];
        o.y = a1 + bm2[1];
        ((float2*)out)[edge] = o;
    }
}

extern "C" void kernel_launch(void* const* d_in, const int* in_sizes, int n_in,
                              void* d_out, int out_size, void* d_ws, size_t ws_size,
                              hipStream_t stream) {
    const float* x   = (const float*)d_in[0];
    const int*   ei  = (const int*)d_in[1];
    const float* W1l = (const float*)d_in[2];
    const float* b1l = (const float*)d_in[3];
    const float* W1r = (const float*)d_in[4];
    const float* W2l = (const float*)d_in[5];
    const float* b2l = (const float*)d_in[6];
    const float* W2r = (const float*)d_in[7];
    const float* Wm1 = (const float*)d_in[8];
    const float* bm1 = (const float*)d_in[9];
    const float* Wm2 = (const float*)d_in[10];
    const float* bm2 = (const float*)d_in[11];

    const int N = in_sizes[0] / IN_DIM;   // 50000
    const int E = in_sizes[1] / 2;        // 800000
    const int* src = ei;
    const int* dst = ei + E;

    const int NB = (N + SCAN_CHUNK - 1) / SCAN_CHUNK;

    // ---- workspace layout ----
    char* ws = (char*)d_ws;
    size_t off = 0;
    auto alloc = [&](size_t bytes) { void* p = ws + off; off = (off + bytes + 255) & ~(size_t)255; return p; };
    int* deg       = (int*)alloc((size_t)N * 4);
    int* row_start = (int*)alloc((size_t)N * 4);
    int* cursor    = (int*)alloc((size_t)N * 4);
    int* partials  = (int*)alloc((size_t)(NB + 1) * 4);
    int* csr_src   = (int*)alloc((size_t)E * 4);
    size_t matB = (size_t)N * HID * sizeof(float);
    float* bufA = (float*)alloc(matB);
    float* bufB = (float*)alloc(matB);
    float* bufC = (float*)alloc(matB);
    float* out = (float*)d_out;

    dim3 gg(HID / GN, (N + GM - 1) / GM);
    int ewg = (E + 3) / 4;
    int nwg = (N + 3) / 4;

    // ---- build CSR (by dst) ----
    hipMemsetAsync(deg, 0, (size_t)N * 4, stream);
    k_count_deg<<<(E + 255) / 256, 256, 0, stream>>>(dst, deg, E);
    k_chunk_sum<<<NB, 64, 0, stream>>>(deg, partials, N);
    k_scan_partials<<<1, 64, 0, stream>>>(partials, NB);
    k_scan_chunks<<<NB, 64, 0, stream>>>(deg, partials, row_start, cursor, N);
    k_bucket<<<(E + 255) / 256, 256, 0, stream>>>(src, dst, cursor, csr_src, E);

    // ---- conv1: agg(mean) -> bufA ; h1 -> bufB ----
    k_gather<<<nwg, 256, 0, stream>>>(x, csr_src, row_start, deg, bufA, N);
    k_gemm<<<gg, 256, 0, stream>>>(bufA, W1l, IN_DIM, x, W1r, IN_DIM, b1l, 1, bufB, N, HID);

    // ---- conv2: agg -> bufA ; h2 -> bufC ----
    k_gather<<<nwg, 256, 0, stream>>>(bufB, csr_src, row_start, deg, bufA, N);
    k_gemm<<<gg, 256, 0, stream>>>(bufA, W2l, HID, bufB, W2r, HID, b2l, 1, bufC, N, HID);

    // ---- P = h2 @ Wm1_top -> bufA ; Q = h2 @ Wm1_bot -> bufB ----
    k_gemm<<<gg, 256, 0, stream>>>(bufC, Wm1, HID, nullptr, nullptr, 0, nullptr, 0, bufA, N, HID);
    k_gemm<<<gg, 256, 0, stream>>>(bufC, Wm1 + (size_t)HID * HID, HID, nullptr, nullptr, 0, nullptr, 0, bufB, N, HID);

    // ---- edge MLP -> logits ----
    k_edge<<<ewg, 256, 0, stream>>>(bufA, bufB, src, dst, bm1, Wm2, bm2, out, E);
}

// Round 3
// 724.998 us; speedup vs baseline: 8.7081x; 1.6374x over previous
//
#include <hip/hip_runtime.h>

#define IN_DIM 256
#define HID 256
#define SCAN_CHUNK 512

typedef unsigned short ushort_t;
typedef __attribute__((ext_vector_type(8))) short short8;
typedef __attribute__((ext_vector_type(4))) float floatx4;

__device__ __forceinline__ float b2f(ushort_t h) {
    union { unsigned int u; float f; } c; c.u = ((unsigned int)h) << 16; return c.f;
}
__device__ __forceinline__ ushort_t f2b(float f) {  // round-to-nearest-even
    union { float f; unsigned int u; } c; c.f = f;
    unsigned int u = c.u;
    unsigned int r = (u + 0x7fffu + ((u >> 16) & 1u)) >> 16;
    return (ushort_t)r;
}

// ---------------- degree ----------------
__global__ void k_count_deg(const int* __restrict__ dst, int* __restrict__ deg, int E) {
    int e = blockIdx.x * blockDim.x + threadIdx.x;
    if (e < E) atomicAdd(&deg[dst[e]], 1);
}

// ---------------- scan ----------------
__global__ __launch_bounds__(64) void k_chunk_sum(const int* __restrict__ deg,
                                                  int* __restrict__ partials, int N) {
    int lane = threadIdx.x;
    int base = blockIdx.x * SCAN_CHUNK + lane * 8;
    int s = 0;
#pragma unroll
    for (int i = 0; i < 8; ++i) s += (base + i < N) ? deg[base + i] : 0;
#pragma unroll
    for (int off = 32; off > 0; off >>= 1) s += __shfl_down(s, off, 64);
    if (lane == 0) partials[blockIdx.x] = s;
}

__global__ void k_scan_partials(int* __restrict__ partials, int nb) {
    if (threadIdx.x == 0 && blockIdx.x == 0) {
        int run = 0;
        for (int i = 0; i < nb; ++i) { int v = partials[i]; partials[i] = run; run += v; }
    }
}

__global__ __launch_bounds__(64) void k_scan_chunks(const int* __restrict__ deg,
                                                    const int* __restrict__ partials,
                                                    int* __restrict__ row_start,
                                                    int* __restrict__ cursor, int N) {
    int lane = threadIdx.x;
    int base = blockIdx.x * SCAN_CHUNK + lane * 8;
    int v[8]; int lsum = 0;
#pragma unroll
    for (int i = 0; i < 8; ++i) { v[i] = (base + i < N) ? deg[base + i] : 0; lsum += v[i]; }
    int pre = lsum;
#pragma unroll
    for (int off = 1; off < 64; off <<= 1) {
        int t = __shfl_up(pre, off, 64);
        if (lane >= off) pre += t;
    }
    pre -= lsum;
    int run = partials[blockIdx.x] + pre;
#pragma unroll
    for (int i = 0; i < 8; ++i) {
        if (base + i < N) { row_start[base + i] = run; cursor[base + i] = run; }
        run += v[i];
    }
}

__global__ void k_bucket(const int* __restrict__ src, const int* __restrict__ dst,
                         int* __restrict__ cursor, int* __restrict__ csr_src, int E) {
    int e = blockIdx.x * blockDim.x + threadIdx.x;
    if (e < E) {
        int pos = atomicAdd(&cursor[dst[e]], 1);
        csr_src[pos] = src[e];
    }
}

// ---------------- cast x -> bf16 ----------------
__global__ __launch_bounds__(256) void k_cast(const float* __restrict__ x,
                                              ushort_t* __restrict__ xb, int n4) {
    int i = blockIdx.x * blockDim.x + threadIdx.x;
    if (i >= n4) return;
    float4 v = ((const float4*)x)[i];
    ushort4 o;
    o.x = f2b(v.x); o.y = f2b(v.y); o.z = f2b(v.z); o.w = f2b(v.w);
    ((ushort4*)xb)[i] = o;
}

// ---------------- weight prep: fp32 [256][256] -> MFMA B-frag order, hi/lo bf16 ----------------
// WF layout: [(kb*nbTot + nb)*2 + plane][512] ushorts; within: lane*8 + j
// element: k = kb*32 + (lane>>4)*8 + j ; n_local = nbL*16 + (lane&15)
__global__ __launch_bounds__(64) void k_wprep(const float* __restrict__ Wsrc,
                                              ushort_t* __restrict__ WF,
                                              int nbTot, int nb0) {
    int lane = threadIdx.x;
    int kb = blockIdx.x >> 4, nbL = blockIdx.x & 15;
    int k = kb * 32 + (lane >> 4) * 8;
    int n = nbL * 16 + (lane & 15);
    size_t dstb = ((size_t)(kb * nbTot + nb0 + nbL) * 2) * 512 + lane * 8;
#pragma unroll
    for (int j = 0; j < 8; ++j) {
        float w = Wsrc[(size_t)(k + j) * 256 + n];
        ushort_t hi = f2b(w);
        ushort_t lo = f2b(w - b2f(hi));
        WF[dstb + j] = hi;
        WF[dstb + 512 + j] = lo;
    }
}

// ---------------- gather-aggregate (bf16 in/out): one wave per node, 4 ch/lane ----------------
__global__ __launch_bounds__(256) void k_gather(const ushort_t* __restrict__ X,
                                                const int* __restrict__ csr_src,
                                                const int* __restrict__ row_start,
                                                const int* __restrict__ deg,
                                                ushort_t* __restrict__ agg, int N) {
    int lane = threadIdx.x & 63;
    int node = blockIdx.x * 4 + (threadIdx.x >> 6);
    if (node >= N) return;
    int start = row_start[node];
    int cnt = deg[node];
    const int* sp = csr_src + start;
    float a0 = 0.f, a1 = 0.f, a2 = 0.f, a3 = 0.f;
    for (int j = 0; j < cnt; ++j) {
        int s = sp[j];
        ushort4 v = ((const ushort4*)(X + (size_t)s * HID))[lane];
        a0 += b2f(v.x); a1 += b2f(v.y); a2 += b2f(v.z); a3 += b2f(v.w);
    }
    float sc = 1.0f / (float)max(cnt, 1);
    ushort4 o;
    o.x = f2b(a0 * sc); o.y = f2b(a1 * sc); o.z = f2b(a2 * sc); o.w = f2b(a3 * sc);
    ((ushort4*)(agg + (size_t)node * HID))[lane] = o;
}

// ---------------- MFMA GEMM: C = act( A1@W1 + A2@W2 + bias ), K=256 per operand ----------------
// A row-major bf16 [M][256]; WF in frag order (hi/lo); C bf16 [M][nbTot*16].
// 64x64 tile, 256 thr = 4 waves in 2x2 grid; each wave 2x2 16x16 MFMA tiles.
__global__ __launch_bounds__(256) void k_mfma(const ushort_t* __restrict__ A1,
                                              const ushort_t* __restrict__ WF1,
                                              const ushort_t* __restrict__ A2,
                                              const ushort_t* __restrict__ WF2,
                                              const float* __restrict__ bias, int relu,
                                              int M, int nbTot,
                                              ushort_t* __restrict__ C) {
    __shared__ ushort_t As[64 * 32];  // [row][k] bf16, 4 KB
    const int tid = threadIdx.x;
    const int lane = tid & 63;
    const int w = tid >> 6;
    const int wm = w >> 1, wn = w & 1;
    const int quad = lane >> 4, l16 = lane & 15;
    const int m0 = blockIdx.y * 64;
    const int n0 = blockIdx.x * 64;
    const int Nout = nbTot * 16;

    // staging map: thread t -> row t>>2, k-quad t&3 (16B each)
    const int srow = tid >> 2, skq = tid & 3;
    int arow = m0 + srow; if (arow >= M) arow = M - 1;

    floatx4 acc[2][2] = {};

    for (int op = 0; op < 2; ++op) {
        const ushort_t* A = op ? A2 : A1;
        const ushort_t* WF = op ? WF2 : WF1;
        if (A == nullptr) continue;
        for (int kb = 0; kb < 8; ++kb) {
            __syncthreads();
            *(uint4*)&As[srow * 32 + skq * 8] =
                *(const uint4*)(A + (size_t)arow * 256 + kb * 32 + skq * 8);
            __syncthreads();

            short8 a0 = *(const short8*)&As[(wm * 32 + l16) * 32 + quad * 8];
            short8 a1 = *(const short8*)&As[(wm * 32 + 16 + l16) * 32 + quad * 8];

            const int nbBase = (n0 >> 4) + wn * 2;
            const ushort_t* wp = WF + ((size_t)(kb * nbTot + nbBase) * 2) * 512 + lane * 8;
            short8 bh0 = *(const short8*)(wp);
            short8 bl0 = *(const short8*)(wp + 512);
            short8 bh1 = *(const short8*)(wp + 1024);
            short8 bl1 = *(const short8*)(wp + 1536);

            acc[0][0] = __builtin_amdgcn_mfma_f32_16x16x32_bf16(a0, bh0, acc[0][0], 0, 0, 0);
            acc[0][0] = __builtin_amdgcn_mfma_f32_16x16x32_bf16(a0, bl0, acc[0][0], 0, 0, 0);
            acc[0][1] = __builtin_amdgcn_mfma_f32_16x16x32_bf16(a0, bh1, acc[0][1], 0, 0, 0);
            acc[0][1] = __builtin_amdgcn_mfma_f32_16x16x32_bf16(a0, bl1, acc[0][1], 0, 0, 0);
            acc[1][0] = __builtin_amdgcn_mfma_f32_16x16x32_bf16(a1, bh0, acc[1][0], 0, 0, 0);
            acc[1][0] = __builtin_amdgcn_mfma_f32_16x16x32_bf16(a1, bl0, acc[1][0], 0, 0, 0);
            acc[1][1] = __builtin_amdgcn_mfma_f32_16x16x32_bf16(a1, bh1, acc[1][1], 0, 0, 0);
            acc[1][1] = __builtin_amdgcn_mfma_f32_16x16x32_bf16(a1, bl1, acc[1][1], 0, 0, 0);
        }
    }

    // epilogue: C/D layout col=lane&15, row=(lane>>4)*4+reg
#pragma unroll
    for (int mi = 0; mi < 2; ++mi) {
#pragma unroll
        for (int nj = 0; nj < 2; ++nj) {
            int col = n0 + wn * 32 + nj * 16 + l16;
            float b = bias ? bias[col] : 0.f;
            int rbase = m0 + wm * 32 + mi * 16 + quad * 4;
#pragma unroll
            for (int reg = 0; reg < 4; ++reg) {
                int r = rbase + reg;
                if (r >= M) continue;
                float v = acc[mi][nj][reg] + b;
                if (relu) v = fmaxf(v, 0.f);
                C[(size_t)r * Nout + col] = f2b(v);
            }
        }
    }
}

// ---------------- edge MLP: logits[e] = relu(P[src]+Q[dst]+bm1) @ Wm2 + bm2 ----------------
// PQ packed bf16 [M][512]: cols 0..255 = P, 256..511 = Q
__global__ __launch_bounds__(256) void k_edge(const ushort_t* __restrict__ PQ,
                                              const int* __restrict__ src,
                                              const int* __restrict__ dst,
                                              const float* __restrict__ bm1,
                                              const float* __restrict__ Wm2,
                                              const float* __restrict__ bm2,
                                              float* __restrict__ out, int E) {
    int lane = threadIdx.x & 63;
    int edge = blockIdx.x * 4 + (threadIdx.x >> 6);
    if (edge >= E) return;
    int s = src[edge], d = dst[edge];
    ushort4 pu = *(const ushort4*)(PQ + (size_t)s * 512 + lane * 4);
    ushort4 qu = *(const ushort4*)(PQ + (size_t)d * 512 + 256 + lane * 4);
    float4 b = ((const float4*)bm1)[lane];
    float h0 = fmaxf(b2f(pu.x) + b2f(qu.x) + b.x, 0.f);
    float h1 = fmaxf(b2f(pu.y) + b2f(qu.y) + b.y, 0.f);
    float h2 = fmaxf(b2f(pu.z) + b2f(qu.z) + b.z, 0.f);
    float h3 = fmaxf(b2f(pu.w) + b2f(qu.w) + b.w, 0.f);
    float4 w01 = ((const float4*)Wm2)[lane * 2];
    float4 w23 = ((const float4*)Wm2)[lane * 2 + 1];
    float a0 = h0 * w01.x + h1 * w01.z + h2 * w23.x + h3 * w23.z;
    float a1 = h0 * w01.y + h1 * w01.w + h2 * w23.y + h3 * w23.w;
#pragma unroll
    for (int off = 32; off > 0; off >>= 1) {
        a0 += __shfl_down(a0, off, 64);
        a1 += __shfl_down(a1, off, 64);
    }
    if (lane == 0) {
        float2 o;
        o.x = a0 + bm2[0];
        o.y = a1 + bm2[1];
        ((float2*)out)[edge] = o;
    }
}

extern "C" void kernel_launch(void* const* d_in, const int* in_sizes, int n_in,
                              void* d_out, int out_size, void* d_ws, size_t ws_size,
                              hipStream_t stream) {
    const float* x   = (const float*)d_in[0];
    const int*   ei  = (const int*)d_in[1];
    const float* W1l = (const float*)d_in[2];
    const float* b1l = (const float*)d_in[3];
    const float* W1r = (const float*)d_in[4];
    const float* W2l = (const float*)d_in[5];
    const float* b2l = (const float*)d_in[6];
    const float* W2r = (const float*)d_in[7];
    const float* Wm1 = (const float*)d_in[8];
    const float* bm1 = (const float*)d_in[9];
    const float* Wm2 = (const float*)d_in[10];
    const float* bm2 = (const float*)d_in[11];

    const int N = in_sizes[0] / IN_DIM;   // 50000
    const int E = in_sizes[1] / 2;        // 800000
    const int* src = ei;
    const int* dst = ei + E;
    const int NB = (N + SCAN_CHUNK - 1) / SCAN_CHUNK;

    // ---- workspace ----
    char* ws = (char*)d_ws;
    size_t off = 0;
    auto alloc = [&](size_t bytes) { void* p = ws + off; off = (off + bytes + 255) & ~(size_t)255; return p; };
    int* deg       = (int*)alloc((size_t)N * 4);
    int* row_start = (int*)alloc((size_t)N * 4);
    int* cursor    = (int*)alloc((size_t)N * 4);
    int* partials  = (int*)alloc((size_t)(NB + 1) * 4);
    int* csr_src   = (int*)alloc((size_t)E * 4);
    size_t matB = (size_t)N * HID * sizeof(ushort_t);          // 25.6 MB
    ushort_t* xb   = (ushort_t*)alloc(matB);
    ushort_t* aggB = (ushort_t*)alloc(matB);
    ushort_t* h1b  = (ushort_t*)alloc(matB);
    ushort_t* h2b  = (ushort_t*)alloc(matB);
    ushort_t* PQ   = (ushort_t*)alloc((size_t)N * 512 * sizeof(ushort_t));  // 51.2 MB
    size_t wfB  = (size_t)8 * 16 * 2 * 512 * sizeof(ushort_t);  // 256 KB
    ushort_t* WF1l = (ushort_t*)alloc(wfB);
    ushort_t* WF1r = (ushort_t*)alloc(wfB);
    ushort_t* WF2l = (ushort_t*)alloc(wfB);
    ushort_t* WF2r = (ushort_t*)alloc(wfB);
    ushort_t* WFm  = (ushort_t*)alloc(wfB * 2);                 // 512 KB (nbTot=32)
    float* out = (float*)d_out;

    int ewg = (E + 3) / 4;
    int nwg = (N + 3) / 4;
    int mrows = (N + 63) / 64;

    // ---- CSR build ----
    hipMemsetAsync(deg, 0, (size_t)N * 4, stream);
    k_count_deg<<<(E + 255) / 256, 256, 0, stream>>>(dst, deg, E);
    k_chunk_sum<<<NB, 64, 0, stream>>>(deg, partials, N);
    k_scan_partials<<<1, 64, 0, stream>>>(partials, NB);
    k_scan_chunks<<<NB, 64, 0, stream>>>(deg, partials, row_start, cursor, N);
    k_bucket<<<(E + 255) / 256, 256, 0, stream>>>(src, dst, cursor, csr_src, E);

    // ---- casts / weight prep ----
    k_cast<<<(N * HID / 4 + 255) / 256, 256, 0, stream>>>(x, xb, N * HID / 4);
    k_wprep<<<128, 64, 0, stream>>>(W1l, WF1l, 16, 0);
    k_wprep<<<128, 64, 0, stream>>>(W1r, WF1r, 16, 0);
    k_wprep<<<128, 64, 0, stream>>>(W2l, WF2l, 16, 0);
    k_wprep<<<128, 64, 0, stream>>>(W2r, WF2r, 16, 0);
    k_wprep<<<128, 64, 0, stream>>>(Wm1, WFm, 32, 0);
    k_wprep<<<128, 64, 0, stream>>>(Wm1 + (size_t)256 * 256, WFm, 32, 16);

    // ---- conv1 ----
    k_gather<<<nwg, 256, 0, stream>>>(xb, csr_src, row_start, deg, aggB, N);
    k_mfma<<<dim3(4, mrows), 256, 0, stream>>>(aggB, WF1l, xb, WF1r, b1l, 1, N, 16, h1b);

    // ---- conv2 ----
    k_gather<<<nwg, 256, 0, stream>>>(h1b, csr_src, row_start, deg, aggB, N);
    k_mfma<<<dim3(4, mrows), 256, 0, stream>>>(aggB, WF2l, h1b, WF2r, b2l, 1, N, 16, h2b);

    // ---- P|Q fused GEMM -> PQ [N][512] ----
    k_mfma<<<dim3(8, mrows), 256, 0, stream>>>(h2b, WFm, nullptr, nullptr, nullptr, 0, N, 32, PQ);

    // ---- edge MLP ----
    k_edge<<<ewg, 256, 0, stream>>>(PQ, src, dst, bm1, Wm2, bm2, out, E);
}

// Round 4
// 614.554 us; speedup vs baseline: 10.2730x; 1.1797x over previous
//
#include <hip/hip_runtime.h>

#define IN_DIM 256
#define HID 256
#define SCAN_CHUNK 512

typedef unsigned short ushort_t;
typedef __attribute__((ext_vector_type(8))) short short8;
typedef __attribute__((ext_vector_type(4))) float floatx4;

__device__ __forceinline__ float b2f(ushort_t h) {
    union { unsigned int u; float f; } c; c.u = ((unsigned int)h) << 16; return c.f;
}
__device__ __forceinline__ ushort_t f2b(float f) {  // round-to-nearest-even
    union { float f; unsigned int u; } c; c.f = f;
    unsigned int u = c.u;
    unsigned int r = (u + 0x7fffu + ((u >> 16) & 1u)) >> 16;
    return (ushort_t)r;
}

// ---------------- degree ----------------
__global__ void k_count_deg(const int* __restrict__ dst, int* __restrict__ deg, int E) {
    int e = blockIdx.x * blockDim.x + threadIdx.x;
    if (e < E) atomicAdd(&deg[dst[e]], 1);
}

// ---------------- scan ----------------
__global__ __launch_bounds__(64) void k_chunk_sum(const int* __restrict__ deg,
                                                  int* __restrict__ partials, int N) {
    int lane = threadIdx.x;
    int base = blockIdx.x * SCAN_CHUNK + lane * 8;
    int s = 0;
#pragma unroll
    for (int i = 0; i < 8; ++i) s += (base + i < N) ? deg[base + i] : 0;
#pragma unroll
    for (int off = 32; off > 0; off >>= 1) s += __shfl_down(s, off, 64);
    if (lane == 0) partials[blockIdx.x] = s;
}

__global__ void k_scan_partials(int* __restrict__ partials, int nb) {
    if (threadIdx.x == 0 && blockIdx.x == 0) {
        int run = 0;
        for (int i = 0; i < nb; ++i) { int v = partials[i]; partials[i] = run; run += v; }
    }
}

__global__ __launch_bounds__(64) void k_scan_chunks(const int* __restrict__ deg,
                                                    const int* __restrict__ partials,
                                                    int* __restrict__ row_start,
                                                    int* __restrict__ cursor, int N) {
    int lane = threadIdx.x;
    int base = blockIdx.x * SCAN_CHUNK + lane * 8;
    int v[8]; int lsum = 0;
#pragma unroll
    for (int i = 0; i < 8; ++i) { v[i] = (base + i < N) ? deg[base + i] : 0; lsum += v[i]; }
    int pre = lsum;
#pragma unroll
    for (int off = 1; off < 64; off <<= 1) {
        int t = __shfl_up(pre, off, 64);
        if (lane >= off) pre += t;
    }
    pre -= lsum;
    int run = partials[blockIdx.x] + pre;
#pragma unroll
    for (int i = 0; i < 8; ++i) {
        if (base + i < N) { row_start[base + i] = run; cursor[base + i] = run; }
        run += v[i];
    }
}

__global__ void k_bucket(const int* __restrict__ src, const int* __restrict__ dst,
                         int* __restrict__ cursor, int* __restrict__ csr_src,
                         int* __restrict__ csr_eid, int E) {
    int e = blockIdx.x * blockDim.x + threadIdx.x;
    if (e < E) {
        int pos = atomicAdd(&cursor[dst[e]], 1);
        csr_src[pos] = src[e];
        csr_eid[pos] = e;
    }
}

// ---------------- cast x -> bf16 ----------------
__global__ __launch_bounds__(256) void k_cast(const float* __restrict__ x,
                                              ushort_t* __restrict__ xb, int n4) {
    int i = blockIdx.x * blockDim.x + threadIdx.x;
    if (i >= n4) return;
    float4 v = ((const float4*)x)[i];
    ushort4 o;
    o.x = f2b(v.x); o.y = f2b(v.y); o.z = f2b(v.z); o.w = f2b(v.w);
    ((ushort4*)xb)[i] = o;
}

// ---------------- weight prep: fp32 [256][256] -> MFMA B-frag order, hi/lo bf16 ----------------
__global__ __launch_bounds__(64) void k_wprep(const float* __restrict__ Wsrc,
                                              ushort_t* __restrict__ WF,
                                              int nbTot, int nb0) {
    int lane = threadIdx.x;
    int kb = blockIdx.x >> 4, nbL = blockIdx.x & 15;
    int k = kb * 32 + (lane >> 4) * 8;
    int n = nbL * 16 + (lane & 15);
    size_t dstb = ((size_t)(kb * nbTot + nb0 + nbL) * 2) * 512 + lane * 8;
#pragma unroll
    for (int j = 0; j < 8; ++j) {
        float w = Wsrc[(size_t)(k + j) * 256 + n];
        ushort_t hi = f2b(w);
        ushort_t lo = f2b(w - b2f(hi));
        WF[dstb + j] = hi;
        WF[dstb + 512 + j] = lo;
    }
}

// ---------------- gather-aggregate: one wave/node, 2 neighbors/iter, 8 ch/lane ----------------
__global__ __launch_bounds__(256) void k_gather(const ushort_t* __restrict__ X,
                                                const int* __restrict__ csr_src,
                                                const int* __restrict__ row_start,
                                                const int* __restrict__ deg,
                                                ushort_t* __restrict__ agg, int N) {
    int lane = threadIdx.x & 63;
    int node = blockIdx.x * 4 + (threadIdx.x >> 6);
    if (node >= N) return;
    int half = lane >> 5, l32 = lane & 31;
    int start = row_start[node];
    int cnt = deg[node];
    const int* sp = csr_src + start;
    float acc[8] = {};
    for (int j = half; j < cnt; j += 2) {
        int s = sp[j];
        short8 v = *(const short8*)(X + (size_t)s * HID + l32 * 8);
#pragma unroll
        for (int i = 0; i < 8; ++i) acc[i] += b2f((ushort_t)v[i]);
    }
#pragma unroll
    for (int i = 0; i < 8; ++i) acc[i] += __shfl_down(acc[i], 32, 64);
    if (half == 0) {
        float sc = 1.0f / (float)max(cnt, 1);
        short8 o;
#pragma unroll
        for (int i = 0; i < 8; ++i) o[i] = (short)f2b(acc[i] * sc);
        *(short8*)(agg + (size_t)node * HID + l32 * 8) = o;
    }
}

// ---------------- MFMA GEMM: C = act( A1@W1 + A2@W2 + bias ), K=256 per operand ----------------
// C row-stride fixed 256; if C2 != null, cols >=256 go to C2 (P|Q split).
__global__ __launch_bounds__(256) void k_mfma(const ushort_t* __restrict__ A1,
                                              const ushort_t* __restrict__ WF1,
                                              const ushort_t* __restrict__ A2,
                                              const ushort_t* __restrict__ WF2,
                                              const float* __restrict__ bias, int relu,
                                              int M, int nbTot,
                                              ushort_t* __restrict__ C,
                                              ushort_t* __restrict__ C2) {
    __shared__ ushort_t As[64 * 32];
    const int tid = threadIdx.x;
    const int lane = tid & 63;
    const int w = tid >> 6;
    const int wm = w >> 1, wn = w & 1;
    const int quad = lane >> 4, l16 = lane & 15;
    const int m0 = blockIdx.y * 64;
    const int n0 = blockIdx.x * 64;

    const int srow = tid >> 2, skq = tid & 3;
    int arow = m0 + srow; if (arow >= M) arow = M - 1;

    floatx4 acc[2][2] = {};

    for (int op = 0; op < 2; ++op) {
        const ushort_t* A = op ? A2 : A1;
        const ushort_t* WF = op ? WF2 : WF1;
        if (A == nullptr) continue;
        for (int kb = 0; kb < 8; ++kb) {
            __syncthreads();
            *(uint4*)&As[srow * 32 + skq * 8] =
                *(const uint4*)(A + (size_t)arow * 256 + kb * 32 + skq * 8);
            __syncthreads();

            short8 a0 = *(const short8*)&As[(wm * 32 + l16) * 32 + quad * 8];
            short8 a1 = *(const short8*)&As[(wm * 32 + 16 + l16) * 32 + quad * 8];

            const int nbBase = (n0 >> 4) + wn * 2;
            const ushort_t* wp = WF + ((size_t)(kb * nbTot + nbBase) * 2) * 512 + lane * 8;
            short8 bh0 = *(const short8*)(wp);
            short8 bl0 = *(const short8*)(wp + 512);
            short8 bh1 = *(const short8*)(wp + 1024);
            short8 bl1 = *(const short8*)(wp + 1536);

            acc[0][0] = __builtin_amdgcn_mfma_f32_16x16x32_bf16(a0, bh0, acc[0][0], 0, 0, 0);
            acc[0][0] = __builtin_amdgcn_mfma_f32_16x16x32_bf16(a0, bl0, acc[0][0], 0, 0, 0);
            acc[0][1] = __builtin_amdgcn_mfma_f32_16x16x32_bf16(a0, bh1, acc[0][1], 0, 0, 0);
            acc[0][1] = __builtin_amdgcn_mfma_f32_16x16x32_bf16(a0, bl1, acc[0][1], 0, 0, 0);
            acc[1][0] = __builtin_amdgcn_mfma_f32_16x16x32_bf16(a1, bh0, acc[1][0], 0, 0, 0);
            acc[1][0] = __builtin_amdgcn_mfma_f32_16x16x32_bf16(a1, bl0, acc[1][0], 0, 0, 0);
            acc[1][1] = __builtin_amdgcn_mfma_f32_16x16x32_bf16(a1, bh1, acc[1][1], 0, 0, 0);
            acc[1][1] = __builtin_amdgcn_mfma_f32_16x16x32_bf16(a1, bl1, acc[1][1], 0, 0, 0);
        }
    }

#pragma unroll
    for (int mi = 0; mi < 2; ++mi) {
#pragma unroll
        for (int nj = 0; nj < 2; ++nj) {
            int col = n0 + wn * 32 + nj * 16 + l16;
            float b = bias ? bias[col] : 0.f;
            int rbase = m0 + wm * 32 + mi * 16 + quad * 4;
            ushort_t* dstp = C;
            int c = col;
            if (C2 && col >= 256) { dstp = C2; c = col - 256; }
#pragma unroll
            for (int reg = 0; reg < 4; ++reg) {
                int r = rbase + reg;
                if (r >= M) continue;
                float v = acc[mi][nj][reg] + b;
                if (relu) v = fmaxf(v, 0.f);
                dstp[(size_t)r * 256 + c] = f2b(v);
            }
        }
    }
}

// ---------------- edge MLP (CSR by dst): one wave/node, 2 edges/iter, 8 ch/lane ----------------
// logits[eid] = relu(P[src]+Q[dst]+bm1) @ Wm2 + bm2
__global__ __launch_bounds__(256) void k_edge(const ushort_t* __restrict__ P,
                                              const ushort_t* __restrict__ Q,
                                              const int* __restrict__ csr_src,
                                              const int* __restrict__ csr_eid,
                                              const int* __restrict__ row_start,
                                              const int* __restrict__ deg,
                                              const float* __restrict__ bm1,
                                              const float* __restrict__ Wm2,
                                              const float* __restrict__ bm2,
                                              float* __restrict__ out, int N) {
    int lane = threadIdx.x & 63;
    int node = blockIdx.x * 4 + (threadIdx.x >> 6);
    if (node >= N) return;
    int half = lane >> 5, l32 = lane & 31;
    int start = row_start[node];
    int cnt = deg[node];
    if (cnt == 0) return;

    // per-node invariants: q + bias (f32), Wm2 columns, out bias
    short8 qv = *(const short8*)(Q + (size_t)node * HID + l32 * 8);
    float qb[8], w0[8], w1[8];
    const float* bp = bm1 + l32 * 8;
    const float* wp = Wm2 + (size_t)l32 * 16;   // rows l32*8.., 2 floats each
#pragma unroll
    for (int i = 0; i < 8; ++i) {
        qb[i] = b2f((ushort_t)qv[i]) + bp[i];
        w0[i] = wp[2 * i];
        w1[i] = wp[2 * i + 1];
    }
    float bo0 = bm2[0], bo1 = bm2[1];

    const int* sp = csr_src + start;
    const int* ep = csr_eid + start;
    for (int j = 0; j < cnt; j += 2) {
        int jj = j + half;
        bool valid = jj < cnt;
        int s = sp[valid ? jj : j];
        short8 pv = *(const short8*)(P + (size_t)s * HID + l32 * 8);
        float a0 = 0.f, a1 = 0.f;
#pragma unroll
        for (int i = 0; i < 8; ++i) {
            float h = fmaxf(b2f((ushort_t)pv[i]) + qb[i], 0.f);
            a0 += h * w0[i];
            a1 += h * w1[i];
        }
#pragma unroll
        for (int off = 16; off > 0; off >>= 1) {
            a0 += __shfl_down(a0, off, 32);
            a1 += __shfl_down(a1, off, 32);
        }
        if (l32 == 0 && valid) {
            int eid = ep[jj];
            float2 o; o.x = a0 + bo0; o.y = a1 + bo1;
            ((float2*)out)[eid] = o;
        }
    }
}

extern "C" void kernel_launch(void* const* d_in, const int* in_sizes, int n_in,
                              void* d_out, int out_size, void* d_ws, size_t ws_size,
                              hipStream_t stream) {
    const float* x   = (const float*)d_in[0];
    const int*   ei  = (const int*)d_in[1];
    const float* W1l = (const float*)d_in[2];
    const float* b1l = (const float*)d_in[3];
    const float* W1r = (const float*)d_in[4];
    const float* W2l = (const float*)d_in[5];
    const float* b2l = (const float*)d_in[6];
    const float* W2r = (const float*)d_in[7];
    const float* Wm1 = (const float*)d_in[8];
    const float* bm1 = (const float*)d_in[9];
    const float* Wm2 = (const float*)d_in[10];
    const float* bm2 = (const float*)d_in[11];

    const int N = in_sizes[0] / IN_DIM;   // 50000
    const int E = in_sizes[1] / 2;        // 800000
    const int* src = ei;
    const int* dst = ei + E;
    const int NB = (N + SCAN_CHUNK - 1) / SCAN_CHUNK;

    // ---- workspace ----
    char* ws = (char*)d_ws;
    size_t off = 0;
    auto alloc = [&](size_t bytes) { void* p = ws + off; off = (off + bytes + 255) & ~(size_t)255; return p; };
    int* deg       = (int*)alloc((size_t)N * 4);
    int* row_start = (int*)alloc((size_t)N * 4);
    int* cursor    = (int*)alloc((size_t)N * 4);
    int* partials  = (int*)alloc((size_t)(NB + 1) * 4);
    int* csr_src   = (int*)alloc((size_t)E * 4);
    int* csr_eid   = (int*)alloc((size_t)E * 4);
    size_t matB = (size_t)N * HID * sizeof(ushort_t);          // 25.6 MB
    ushort_t* xb   = (ushort_t*)alloc(matB);
    ushort_t* aggB = (ushort_t*)alloc(matB);
    ushort_t* h1b  = (ushort_t*)alloc(matB);
    ushort_t* h2b  = (ushort_t*)alloc(matB);
    ushort_t* Pb   = (ushort_t*)alloc(matB);
    ushort_t* Qb   = (ushort_t*)alloc(matB);
    size_t wfB  = (size_t)8 * 16 * 2 * 512 * sizeof(ushort_t);  // 256 KB
    ushort_t* WF1l = (ushort_t*)alloc(wfB);
    ushort_t* WF1r = (ushort_t*)alloc(wfB);
    ushort_t* WF2l = (ushort_t*)alloc(wfB);
    ushort_t* WF2r = (ushort_t*)alloc(wfB);
    ushort_t* WFm  = (ushort_t*)alloc(wfB * 2);                 // nbTot=32
    float* out = (float*)d_out;

    int nwg = (N + 3) / 4;
    int mrows = (N + 63) / 64;

    // ---- CSR build ----
    hipMemsetAsync(deg, 0, (size_t)N * 4, stream);
    k_count_deg<<<(E + 255) / 256, 256, 0, stream>>>(dst, deg, E);
    k_chunk_sum<<<NB, 64, 0, stream>>>(deg, partials, N);
    k_scan_partials<<<1, 64, 0, stream>>>(partials, NB);
    k_scan_chunks<<<NB, 64, 0, stream>>>(deg, partials, row_start, cursor, N);
    k_bucket<<<(E + 255) / 256, 256, 0, stream>>>(src, dst, cursor, csr_src, csr_eid, E);

    // ---- casts / weight prep ----
    k_cast<<<(N * HID / 4 + 255) / 256, 256, 0, stream>>>(x, xb, N * HID / 4);
    k_wprep<<<128, 64, 0, stream>>>(W1l, WF1l, 16, 0);
    k_wprep<<<128, 64, 0, stream>>>(W1r, WF1r, 16, 0);
    k_wprep<<<128, 64, 0, stream>>>(W2l, WF2l, 16, 0);
    k_wprep<<<128, 64, 0, stream>>>(W2r, WF2r, 16, 0);
    k_wprep<<<128, 64, 0, stream>>>(Wm1, WFm, 32, 0);
    k_wprep<<<128, 64, 0, stream>>>(Wm1 + (size_t)256 * 256, WFm, 32, 16);

    // ---- conv1 ----
    k_gather<<<nwg, 256, 0, stream>>>(xb, csr_src, row_start, deg, aggB, N);
    k_mfma<<<dim3(4, mrows), 256, 0, stream>>>(aggB, WF1l, xb, WF1r, b1l, 1, N, 16, h1b, nullptr);

    // ---- conv2 ----
    k_gather<<<nwg, 256, 0, stream>>>(h1b, csr_src, row_start, deg, aggB, N);
    k_mfma<<<dim3(4, mrows), 256, 0, stream>>>(aggB, WF2l, h1b, WF2r, b2l, 1, N, 16, h2b, nullptr);

    // ---- P|Q fused GEMM -> Pb, Qb ----
    k_mfma<<<dim3(8, mrows), 256, 0, stream>>>(h2b, WFm, nullptr, nullptr, nullptr, 0, N, 32, Pb, Qb);

    // ---- edge MLP (CSR order) ----
    k_edge<<<nwg, 256, 0, stream>>>(Pb, Qb, csr_src, csr_eid, row_start, deg, bm1, Wm2, bm2, out, N);
}

// Round 5
// 613.779 us; speedup vs baseline: 10.2860x; 1.0013x over previous
//
#include <hip/hip_runtime.h>

#define IN_DIM 256
#define HID 256
#define SCAN_CHUNK 512

typedef unsigned short ushort_t;
typedef __attribute__((ext_vector_type(8))) short short8;
typedef __attribute__((ext_vector_type(4))) float floatx4;

__device__ __forceinline__ float b2f(ushort_t h) {
    union { unsigned int u; float f; } c; c.u = ((unsigned int)h) << 16; return c.f;
}
__device__ __forceinline__ ushort_t f2b(float f) {  // round-to-nearest-even
    union { float f; unsigned int u; } c; c.f = f;
    unsigned int u = c.u;
    unsigned int r = (u + 0x7fffu + ((u >> 16) & 1u)) >> 16;
    return (ushort_t)r;
}

// ---------------- degree ----------------
__global__ void k_count_deg(const int* __restrict__ dst, int* __restrict__ deg, int E) {
    int e = blockIdx.x * blockDim.x + threadIdx.x;
    if (e < E) atomicAdd(&deg[dst[e]], 1);
}

// ---------------- scan ----------------
__global__ __launch_bounds__(64) void k_chunk_sum(const int* __restrict__ deg,
                                                  int* __restrict__ partials, int N) {
    int lane = threadIdx.x;
    int base = blockIdx.x * SCAN_CHUNK + lane * 8;
    int s = 0;
#pragma unroll
    for (int i = 0; i < 8; ++i) s += (base + i < N) ? deg[base + i] : 0;
#pragma unroll
    for (int off = 32; off > 0; off >>= 1) s += __shfl_down(s, off, 64);
    if (lane == 0) partials[blockIdx.x] = s;
}

__global__ void k_scan_partials(int* __restrict__ partials, int nb) {
    if (threadIdx.x == 0 && blockIdx.x == 0) {
        int run = 0;
        for (int i = 0; i < nb; ++i) { int v = partials[i]; partials[i] = run; run += v; }
    }
}

__global__ __launch_bounds__(64) void k_scan_chunks(const int* __restrict__ deg,
                                                    const int* __restrict__ partials,
                                                    int* __restrict__ row_start,
                                                    int* __restrict__ cursor, int N) {
    int lane = threadIdx.x;
    int base = blockIdx.x * SCAN_CHUNK + lane * 8;
    int v[8]; int lsum = 0;
#pragma unroll
    for (int i = 0; i < 8; ++i) { v[i] = (base + i < N) ? deg[base + i] : 0; lsum += v[i]; }
    int pre = lsum;
#pragma unroll
    for (int off = 1; off < 64; off <<= 1) {
        int t = __shfl_up(pre, off, 64);
        if (lane >= off) pre += t;
    }
    pre -= lsum;
    int run = partials[blockIdx.x] + pre;
#pragma unroll
    for (int i = 0; i < 8; ++i) {
        if (base + i < N) { row_start[base + i] = run; cursor[base + i] = run; }
        run += v[i];
    }
}

__global__ void k_bucket(const int* __restrict__ src, const int* __restrict__ dst,
                         int* __restrict__ cursor, int* __restrict__ csr_src,
                         int* __restrict__ csr_eid, int E) {
    int e = blockIdx.x * blockDim.x + threadIdx.x;
    if (e < E) {
        int pos = atomicAdd(&cursor[dst[e]], 1);
        csr_src[pos] = src[e];
        csr_eid[pos] = e;
    }
}

// ---------------- cast x -> bf16 ----------------
__global__ __launch_bounds__(256) void k_cast(const float* __restrict__ x,
                                              ushort_t* __restrict__ xb, int n4) {
    int i = blockIdx.x * blockDim.x + threadIdx.x;
    if (i >= n4) return;
    float4 v = ((const float4*)x)[i];
    ushort4 o;
    o.x = f2b(v.x); o.y = f2b(v.y); o.z = f2b(v.z); o.w = f2b(v.w);
    ((ushort4*)xb)[i] = o;
}

// ---------------- weight prep: fp32 [256][256] -> MFMA B-frag order, hi/lo bf16 ----------------
__global__ __launch_bounds__(64) void k_wprep(const float* __restrict__ Wsrc,
                                              ushort_t* __restrict__ WF,
                                              int nbTot, int nb0) {
    int lane = threadIdx.x;
    int kb = blockIdx.x >> 4, nbL = blockIdx.x & 15;
    int k = kb * 32 + (lane >> 4) * 8;
    int n = nbL * 16 + (lane & 15);
    size_t dstb = ((size_t)(kb * nbTot + nb0 + nbL) * 2) * 512 + lane * 8;
#pragma unroll
    for (int j = 0; j < 8; ++j) {
        float w = Wsrc[(size_t)(k + j) * 256 + n];
        ushort_t hi = f2b(w);
        ushort_t lo = f2b(w - b2f(hi));
        WF[dstb + j] = hi;
        WF[dstb + 512 + j] = lo;
    }
}

// ---------------- gather-aggregate: one wave/node, 4 neighbors/iter, 16 ch/lane ----------------
__global__ __launch_bounds__(256) void k_gather(const ushort_t* __restrict__ X,
                                                const int* __restrict__ csr_src,
                                                const int* __restrict__ row_start,
                                                const int* __restrict__ deg,
                                                ushort_t* __restrict__ agg, int N) {
    int lane = threadIdx.x & 63;
    int node = blockIdx.x * 4 + (threadIdx.x >> 6);
    if (node >= N) return;
    int quad = lane >> 4, l16 = lane & 15;
    int start = row_start[node];
    int cnt = deg[node];
    const int* sp = csr_src + start;
    float acc[16] = {};
    // lane covers channels l16*16 .. +15 ; quad q handles neighbors q, q+4, ...
    for (int j = quad; j < cnt; j += 4) {
        int s = sp[j];
        const ushort_t* row = X + (size_t)s * HID + l16 * 16;
        short8 v0 = *(const short8*)(row);
        short8 v1 = *(const short8*)(row + 8);
#pragma unroll
        for (int i = 0; i < 8; ++i) {
            acc[i]     += b2f((ushort_t)v0[i]);
            acc[8 + i] += b2f((ushort_t)v1[i]);
        }
    }
    // combine the 4 quads (channels identical across quads)
#pragma unroll
    for (int i = 0; i < 16; ++i) {
        acc[i] += __shfl_down(acc[i], 32, 64);
        acc[i] += __shfl_down(acc[i], 16, 64);
    }
    if (quad == 0) {
        float sc = 1.0f / (float)max(cnt, 1);
        short8 o0, o1;
#pragma unroll
        for (int i = 0; i < 8; ++i) {
            o0[i] = (short)f2b(acc[i] * sc);
            o1[i] = (short)f2b(acc[8 + i] * sc);
        }
        ushort_t* op = agg + (size_t)node * HID + l16 * 16;
        *(short8*)(op) = o0;
        *(short8*)(op + 8) = o1;
    }
}

// ---------------- MFMA GEMM: C = act( A1@W1 + A2@W2 + bias ), K=256 per operand ----------------
// C row-stride fixed 256; if C2 != null, cols >=256 go to C2 (P|Q split).
__global__ __launch_bounds__(256) void k_mfma(const ushort_t* __restrict__ A1,
                                              const ushort_t* __restrict__ WF1,
                                              const ushort_t* __restrict__ A2,
                                              const ushort_t* __restrict__ WF2,
                                              const float* __restrict__ bias, int relu,
                                              int M, int nbTot,
                                              ushort_t* __restrict__ C,
                                              ushort_t* __restrict__ C2) {
    __shared__ ushort_t As[64 * 32];
    const int tid = threadIdx.x;
    const int lane = tid & 63;
    const int w = tid >> 6;
    const int wm = w >> 1, wn = w & 1;
    const int quad = lane >> 4, l16 = lane & 15;
    const int m0 = blockIdx.y * 64;
    const int n0 = blockIdx.x * 64;

    const int srow = tid >> 2, skq = tid & 3;
    int arow = m0 + srow; if (arow >= M) arow = M - 1;

    floatx4 acc[2][2] = {};

    for (int op = 0; op < 2; ++op) {
        const ushort_t* A = op ? A2 : A1;
        const ushort_t* WF = op ? WF2 : WF1;
        if (A == nullptr) continue;
        for (int kb = 0; kb < 8; ++kb) {
            __syncthreads();
            *(uint4*)&As[srow * 32 + skq * 8] =
                *(const uint4*)(A + (size_t)arow * 256 + kb * 32 + skq * 8);
            __syncthreads();

            short8 a0 = *(const short8*)&As[(wm * 32 + l16) * 32 + quad * 8];
            short8 a1 = *(const short8*)&As[(wm * 32 + 16 + l16) * 32 + quad * 8];

            const int nbBase = (n0 >> 4) + wn * 2;
            const ushort_t* wp = WF + ((size_t)(kb * nbTot + nbBase) * 2) * 512 + lane * 8;
            short8 bh0 = *(const short8*)(wp);
            short8 bl0 = *(const short8*)(wp + 512);
            short8 bh1 = *(const short8*)(wp + 1024);
            short8 bl1 = *(const short8*)(wp + 1536);

            acc[0][0] = __builtin_amdgcn_mfma_f32_16x16x32_bf16(a0, bh0, acc[0][0], 0, 0, 0);
            acc[0][0] = __builtin_amdgcn_mfma_f32_16x16x32_bf16(a0, bl0, acc[0][0], 0, 0, 0);
            acc[0][1] = __builtin_amdgcn_mfma_f32_16x16x32_bf16(a0, bh1, acc[0][1], 0, 0, 0);
            acc[0][1] = __builtin_amdgcn_mfma_f32_16x16x32_bf16(a0, bl1, acc[0][1], 0, 0, 0);
            acc[1][0] = __builtin_amdgcn_mfma_f32_16x16x32_bf16(a1, bh0, acc[1][0], 0, 0, 0);
            acc[1][0] = __builtin_amdgcn_mfma_f32_16x16x32_bf16(a1, bl0, acc[1][0], 0, 0, 0);
            acc[1][1] = __builtin_amdgcn_mfma_f32_16x16x32_bf16(a1, bh1, acc[1][1], 0, 0, 0);
            acc[1][1] = __builtin_amdgcn_mfma_f32_16x16x32_bf16(a1, bl1, acc[1][1], 0, 0, 0);
        }
    }

#pragma unroll
    for (int mi = 0; mi < 2; ++mi) {
#pragma unroll
        for (int nj = 0; nj < 2; ++nj) {
            int col = n0 + wn * 32 + nj * 16 + l16;
            float b = bias ? bias[col] : 0.f;
            int rbase = m0 + wm * 32 + mi * 16 + quad * 4;
            ushort_t* dstp = C;
            int c = col;
            if (C2 && col >= 256) { dstp = C2; c = col - 256; }
#pragma unroll
            for (int reg = 0; reg < 4; ++reg) {
                int r = rbase + reg;
                if (r >= M) continue;
                float v = acc[mi][nj][reg] + b;
                if (relu) v = fmaxf(v, 0.f);
                dstp[(size_t)r * 256 + c] = f2b(v);
            }
        }
    }
}

// ---------------- edge MLP (CSR by dst): one wave/node, 4 edges/iter, 16 ch/lane ----------------
// logits[eid] = relu(P[src]+Q[dst]+bm1) @ Wm2 + bm2
__global__ __launch_bounds__(256) void k_edge(const ushort_t* __restrict__ P,
                                              const ushort_t* __restrict__ Q,
                                              const int* __restrict__ csr_src,
                                              const int* __restrict__ csr_eid,
                                              const int* __restrict__ row_start,
                                              const int* __restrict__ deg,
                                              const float* __restrict__ bm1,
                                              const float* __restrict__ Wm2,
                                              const float* __restrict__ bm2,
                                              float* __restrict__ out, int N) {
    int lane = threadIdx.x & 63;
    int node = blockIdx.x * 4 + (threadIdx.x >> 6);
    if (node >= N) return;
    int quad = lane >> 4, l16 = lane & 15;
    int start = row_start[node];
    int cnt = deg[node];
    if (cnt == 0) return;

    // per-node invariants (broadcast across quads): q + bias, Wm2 columns
    const ushort_t* qrow = Q + (size_t)node * HID + l16 * 16;
    short8 q0 = *(const short8*)(qrow);
    short8 q1 = *(const short8*)(qrow + 8);
    float qb[16], w0[16], w1[16];
    const float* bp = bm1 + l16 * 16;
    const float2* wp = (const float2*)Wm2 + l16 * 16;
#pragma unroll
    for (int i = 0; i < 8; ++i) {
        qb[i]     = b2f((ushort_t)q0[i]) + bp[i];
        qb[8 + i] = b2f((ushort_t)q1[i]) + bp[8 + i];
    }
#pragma unroll
    for (int i = 0; i < 16; ++i) {
        float2 wv = wp[i];
        w0[i] = wv.x; w1[i] = wv.y;
    }
    float bo0 = bm2[0], bo1 = bm2[1];

    const int* sp = csr_src + start;
    const int* ep = csr_eid + start;
    for (int j0 = 0; j0 < cnt; j0 += 4) {
        int jj = j0 + quad;
        bool valid = jj < cnt;
        int s = sp[valid ? jj : cnt - 1];
        const ushort_t* prow = P + (size_t)s * HID + l16 * 16;
        short8 p0 = *(const short8*)(prow);
        short8 p1 = *(const short8*)(prow + 8);
        float a0 = 0.f, a1 = 0.f;
#pragma unroll
        for (int i = 0; i < 8; ++i) {
            float h = fmaxf(b2f((ushort_t)p0[i]) + qb[i], 0.f);
            a0 += h * w0[i];
            a1 += h * w1[i];
        }
#pragma unroll
        for (int i = 0; i < 8; ++i) {
            float h = fmaxf(b2f((ushort_t)p1[i]) + qb[8 + i], 0.f);
            a0 += h * w0[8 + i];
            a1 += h * w1[8 + i];
        }
#pragma unroll
        for (int off = 8; off > 0; off >>= 1) {
            a0 += __shfl_down(a0, off, 16);
            a1 += __shfl_down(a1, off, 16);
        }
        if (l16 == 0 && valid) {
            int eid = ep[jj];
            float2 o; o.x = a0 + bo0; o.y = a1 + bo1;
            ((float2*)out)[eid] = o;
        }
    }
}

extern "C" void kernel_launch(void* const* d_in, const int* in_sizes, int n_in,
                              void* d_out, int out_size, void* d_ws, size_t ws_size,
                              hipStream_t stream) {
    const float* x   = (const float*)d_in[0];
    const int*   ei  = (const int*)d_in[1];
    const float* W1l = (const float*)d_in[2];
    const float* b1l = (const float*)d_in[3];
    const float* W1r = (const float*)d_in[4];
    const float* W2l = (const float*)d_in[5];
    const float* b2l = (const float*)d_in[6];
    const float* W2r = (const float*)d_in[7];
    const float* Wm1 = (const float*)d_in[8];
    const float* bm1 = (const float*)d_in[9];
    const float* Wm2 = (const float*)d_in[10];
    const float* bm2 = (const float*)d_in[11];

    const int N = in_sizes[0] / IN_DIM;   // 50000
    const int E = in_sizes[1] / 2;        // 800000
    const int* src = ei;
    const int* dst = ei + E;
    const int NB = (N + SCAN_CHUNK - 1) / SCAN_CHUNK;

    // ---- workspace ----
    char* ws = (char*)d_ws;
    size_t off = 0;
    auto alloc = [&](size_t bytes) { void* p = ws + off; off = (off + bytes + 255) & ~(size_t)255; return p; };
    int* deg       = (int*)alloc((size_t)N * 4);
    int* row_start = (int*)alloc((size_t)N * 4);
    int* cursor    = (int*)alloc((size_t)N * 4);
    int* partials  = (int*)alloc((size_t)(NB + 1) * 4);
    int* csr_src   = (int*)alloc((size_t)E * 4);
    int* csr_eid   = (int*)alloc((size_t)E * 4);
    size_t matB = (size_t)N * HID * sizeof(ushort_t);          // 25.6 MB
    ushort_t* xb   = (ushort_t*)alloc(matB);
    ushort_t* aggB = (ushort_t*)alloc(matB);
    ushort_t* h1b  = (ushort_t*)alloc(matB);
    ushort_t* h2b  = (ushort_t*)alloc(matB);
    ushort_t* Pb   = (ushort_t*)alloc(matB);
    ushort_t* Qb   = (ushort_t*)alloc(matB);
    size_t wfB  = (size_t)8 * 16 * 2 * 512 * sizeof(ushort_t);  // 256 KB
    ushort_t* WF1l = (ushort_t*)alloc(wfB);
    ushort_t* WF1r = (ushort_t*)alloc(wfB);
    ushort_t* WF2l = (ushort_t*)alloc(wfB);
    ushort_t* WF2r = (ushort_t*)alloc(wfB);
    ushort_t* WFm  = (ushort_t*)alloc(wfB * 2);                 // nbTot=32
    float* out = (float*)d_out;

    int nwg = (N + 3) / 4;
    int mrows = (N + 63) / 64;

    // ---- CSR build ----
    hipMemsetAsync(deg, 0, (size_t)N * 4, stream);
    k_count_deg<<<(E + 255) / 256, 256, 0, stream>>>(dst, deg, E);
    k_chunk_sum<<<NB, 64, 0, stream>>>(deg, partials, N);
    k_scan_partials<<<1, 64, 0, stream>>>(partials, NB);
    k_scan_chunks<<<NB, 64, 0, stream>>>(deg, partials, row_start, cursor, N);
    k_bucket<<<(E + 255) / 256, 256, 0, stream>>>(src, dst, cursor, csr_src, csr_eid, E);

    // ---- casts / weight prep ----
    k_cast<<<(N * HID / 4 + 255) / 256, 256, 0, stream>>>(x, xb, N * HID / 4);
    k_wprep<<<128, 64, 0, stream>>>(W1l, WF1l, 16, 0);
    k_wprep<<<128, 64, 0, stream>>>(W1r, WF1r, 16, 0);
    k_wprep<<<128, 64, 0, stream>>>(W2l, WF2l, 16, 0);
    k_wprep<<<128, 64, 0, stream>>>(W2r, WF2r, 16, 0);
    k_wprep<<<128, 64, 0, stream>>>(Wm1, WFm, 32, 0);
    k_wprep<<<128, 64, 0, stream>>>(Wm1 + (size_t)256 * 256, WFm, 32, 16);

    // ---- conv1 ----
    k_gather<<<nwg, 256, 0, stream>>>(xb, csr_src, row_start, deg, aggB, N);
    k_mfma<<<dim3(4, mrows), 256, 0, stream>>>(aggB, WF1l, xb, WF1r, b1l, 1, N, 16, h1b, nullptr);

    // ---- conv2 ----
    k_gather<<<nwg, 256, 0, stream>>>(h1b, csr_src, row_start, deg, aggB, N);
    k_mfma<<<dim3(4, mrows), 256, 0, stream>>>(aggB, WF2l, h1b, WF2r, b2l, 1, N, 16, h2b, nullptr);

    // ---- P|Q fused GEMM -> Pb, Qb ----
    k_mfma<<<dim3(8, mrows), 256, 0, stream>>>(h2b, WFm, nullptr, nullptr, nullptr, 0, N, 32, Pb, Qb);

    // ---- edge MLP (CSR order) ----
    k_edge<<<nwg, 256, 0, stream>>>(Pb, Qb, csr_src, csr_eid, row_start, deg, bm1, Wm2, bm2, out, N);
}

// Round 7
// 590.267 us; speedup vs baseline: 10.6957x; 1.0398x over previous
//
#include <hip/hip_runtime.h>

#define IN_DIM 256
#define HID 256
#define SCAN_CHUNK 512

typedef unsigned short ushort_t;
typedef __attribute__((ext_vector_type(8))) short short8;
typedef __attribute__((ext_vector_type(4))) float floatx4;

__device__ __forceinline__ float b2f(ushort_t h) {
    union { unsigned int u; float f; } c; c.u = ((unsigned int)h) << 16; return c.f;
}
__device__ __forceinline__ ushort_t f2b(float f) {  // round-to-nearest-even
    union { float f; unsigned int u; } c; c.f = f;
    unsigned int u = c.u;
    unsigned int r = (u + 0x7fffu + ((u >> 16) & 1u)) >> 16;
    return (ushort_t)r;
}

// ---------------- degree ----------------
__global__ void k_count_deg(const int* __restrict__ dst, int* __restrict__ deg, int E) {
    int e = blockIdx.x * blockDim.x + threadIdx.x;
    if (e < E) atomicAdd(&deg[dst[e]], 1);
}

// ---------------- scan ----------------
__global__ __launch_bounds__(64) void k_chunk_sum(const int* __restrict__ deg,
                                                  int* __restrict__ partials, int N) {
    int lane = threadIdx.x;
    int base = blockIdx.x * SCAN_CHUNK + lane * 8;
    int s = 0;
#pragma unroll
    for (int i = 0; i < 8; ++i) s += (base + i < N) ? deg[base + i] : 0;
#pragma unroll
    for (int off = 32; off > 0; off >>= 1) s += __shfl_down(s, off, 64);
    if (lane == 0) partials[blockIdx.x] = s;
}

__global__ void k_scan_partials(int* __restrict__ partials, int nb) {
    if (threadIdx.x == 0 && blockIdx.x == 0) {
        int run = 0;
        for (int i = 0; i < nb; ++i) { int v = partials[i]; partials[i] = run; run += v; }
    }
}

__global__ __launch_bounds__(64) void k_scan_chunks(const int* __restrict__ deg,
                                                    const int* __restrict__ partials,
                                                    int* __restrict__ row_start,
                                                    int* __restrict__ cursor, int N) {
    int lane = threadIdx.x;
    int base = blockIdx.x * SCAN_CHUNK + lane * 8;
    int v[8]; int lsum = 0;
#pragma unroll
    for (int i = 0; i < 8; ++i) { v[i] = (base + i < N) ? deg[base + i] : 0; lsum += v[i]; }
    int pre = lsum;
#pragma unroll
    for (int off = 1; off < 64; off <<= 1) {
        int t = __shfl_up(pre, off, 64);
        if (lane >= off) pre += t;
    }
    pre -= lsum;
    int run = partials[blockIdx.x] + pre;
#pragma unroll
    for (int i = 0; i < 8; ++i) {
        if (base + i < N) { row_start[base + i] = run; cursor[base + i] = run; }
        run += v[i];
    }
}

// csr[pos] = {src, eid} packed
__global__ void k_bucket(const int* __restrict__ src, const int* __restrict__ dst,
                         int* __restrict__ cursor, int2* __restrict__ csr, int E) {
    int e = blockIdx.x * blockDim.x + threadIdx.x;
    if (e < E) {
        int pos = atomicAdd(&cursor[dst[e]], 1);
        csr[pos] = make_int2(src[e], e);
    }
}

// ---------------- cast x -> bf16 ----------------
__global__ __launch_bounds__(256) void k_cast(const float* __restrict__ x,
                                              ushort_t* __restrict__ xb, int n4) {
    int i = blockIdx.x * blockDim.x + threadIdx.x;
    if (i >= n4) return;
    float4 v = ((const float4*)x)[i];
    ushort4 o;
    o.x = f2b(v.x); o.y = f2b(v.y); o.z = f2b(v.z); o.w = f2b(v.w);
    ((ushort4*)xb)[i] = o;
}

// ---------------- weight prep: fp32 [256][256] -> MFMA B-frag order, hi/lo bf16 ----------------
__global__ __launch_bounds__(64) void k_wprep(const float* __restrict__ Wsrc,
                                              ushort_t* __restrict__ WF,
                                              int nbTot, int nb0) {
    int lane = threadIdx.x;
    int kb = blockIdx.x >> 4, nbL = blockIdx.x & 15;
    int k = kb * 32 + (lane >> 4) * 8;
    int n = nbL * 16 + (lane & 15);
    size_t dstb = ((size_t)(kb * nbTot + nb0 + nbL) * 2) * 512 + lane * 8;
#pragma unroll
    for (int j = 0; j < 8; ++j) {
        float w = Wsrc[(size_t)(k + j) * 256 + n];
        ushort_t hi = f2b(w);
        ushort_t lo = f2b(w - b2f(hi));
        WF[dstb + j] = hi;
        WF[dstb + 512 + j] = lo;
    }
}

// ---------------- gather-aggregate: one wave/node, 4 neighbors in flight, batched indices ----
// NOTE: inner loop is wave-UNIFORM (j4); per-quad validity is predicated, never branched
// around the __shfl — shfl from an exec=0 lane is undefined (R6 bug).
__global__ __launch_bounds__(256) void k_gather(const ushort_t* __restrict__ X,
                                                const int2* __restrict__ csr,
                                                const int* __restrict__ row_start,
                                                const int* __restrict__ deg,
                                                ushort_t* __restrict__ agg, int N) {
    int lane = threadIdx.x & 63;
    int node = blockIdx.x * 4 + (threadIdx.x >> 6);
    if (node >= N) return;
    int quad = lane >> 4, l16 = lane & 15;
    int start = row_start[node];
    int cnt = deg[node];
    const int2* sp = csr + start;
    float acc[16] = {};
    for (int b = 0; b < cnt; b += 64) {
        int nb = min(64, cnt - b);
        int sidx = (lane < nb) ? sp[b + lane].x : 0;   // one coalesced batch load
        for (int j4 = 0; j4 < nb; j4 += 4) {           // uniform across the wave
            int j = j4 + quad;
            bool valid = j < nb;
            int s = __shfl(sidx, valid ? j : 0, 64);   // full exec at the shfl
            if (valid) {
                const ushort_t* row = X + (size_t)s * HID + l16 * 16;
                short8 v0 = *(const short8*)(row);
                short8 v1 = *(const short8*)(row + 8);
#pragma unroll
                for (int i = 0; i < 8; ++i) {
                    acc[i]     += b2f((ushort_t)v0[i]);
                    acc[8 + i] += b2f((ushort_t)v1[i]);
                }
            }
        }
    }
#pragma unroll
    for (int i = 0; i < 16; ++i) {
        acc[i] += __shfl_down(acc[i], 32, 64);
        acc[i] += __shfl_down(acc[i], 16, 64);
    }
    if (quad == 0) {
        float sc = 1.0f / (float)max(cnt, 1);
        short8 o0, o1;
#pragma unroll
        for (int i = 0; i < 8; ++i) {
            o0[i] = (short)f2b(acc[i] * sc);
            o1[i] = (short)f2b(acc[8 + i] * sc);
        }
        ushort_t* op = agg + (size_t)node * HID + l16 * 16;
        *(short8*)(op) = o0;
        *(short8*)(op + 8) = o1;
    }
}

// ---------------- MFMA GEMM: C = act( A1@W1 + A2@W2 + bias ), K=256 per operand ----------------
__global__ __launch_bounds__(256) void k_mfma(const ushort_t* __restrict__ A1,
                                              const ushort_t* __restrict__ WF1,
                                              const ushort_t* __restrict__ A2,
                                              const ushort_t* __restrict__ WF2,
                                              const float* __restrict__ bias, int relu,
                                              int M, int nbTot,
                                              ushort_t* __restrict__ C,
                                              ushort_t* __restrict__ C2) {
    __shared__ ushort_t As[64 * 32];
    const int tid = threadIdx.x;
    const int lane = tid & 63;
    const int w = tid >> 6;
    const int wm = w >> 1, wn = w & 1;
    const int quad = lane >> 4, l16 = lane & 15;
    const int m0 = blockIdx.y * 64;
    const int n0 = blockIdx.x * 64;

    const int srow = tid >> 2, skq = tid & 3;
    int arow = m0 + srow; if (arow >= M) arow = M - 1;

    floatx4 acc[2][2] = {};

    for (int op = 0; op < 2; ++op) {
        const ushort_t* A = op ? A2 : A1;
        const ushort_t* WF = op ? WF2 : WF1;
        if (A == nullptr) continue;
        for (int kb = 0; kb < 8; ++kb) {
            __syncthreads();
            *(uint4*)&As[srow * 32 + skq * 8] =
                *(const uint4*)(A + (size_t)arow * 256 + kb * 32 + skq * 8);
            __syncthreads();

            short8 a0 = *(const short8*)&As[(wm * 32 + l16) * 32 + quad * 8];
            short8 a1 = *(const short8*)&As[(wm * 32 + 16 + l16) * 32 + quad * 8];

            const int nbBase = (n0 >> 4) + wn * 2;
            const ushort_t* wp = WF + ((size_t)(kb * nbTot + nbBase) * 2) * 512 + lane * 8;
            short8 bh0 = *(const short8*)(wp);
            short8 bl0 = *(const short8*)(wp + 512);
            short8 bh1 = *(const short8*)(wp + 1024);
            short8 bl1 = *(const short8*)(wp + 1536);

            acc[0][0] = __builtin_amdgcn_mfma_f32_16x16x32_bf16(a0, bh0, acc[0][0], 0, 0, 0);
            acc[0][0] = __builtin_amdgcn_mfma_f32_16x16x32_bf16(a0, bl0, acc[0][0], 0, 0, 0);
            acc[0][1] = __builtin_amdgcn_mfma_f32_16x16x32_bf16(a0, bh1, acc[0][1], 0, 0, 0);
            acc[0][1] = __builtin_amdgcn_mfma_f32_16x16x32_bf16(a0, bl1, acc[0][1], 0, 0, 0);
            acc[1][0] = __builtin_amdgcn_mfma_f32_16x16x32_bf16(a1, bh0, acc[1][0], 0, 0, 0);
            acc[1][0] = __builtin_amdgcn_mfma_f32_16x16x32_bf16(a1, bl0, acc[1][0], 0, 0, 0);
            acc[1][1] = __builtin_amdgcn_mfma_f32_16x16x32_bf16(a1, bh1, acc[1][1], 0, 0, 0);
            acc[1][1] = __builtin_amdgcn_mfma_f32_16x16x32_bf16(a1, bl1, acc[1][1], 0, 0, 0);
        }
    }

#pragma unroll
    for (int mi = 0; mi < 2; ++mi) {
#pragma unroll
        for (int nj = 0; nj < 2; ++nj) {
            int col = n0 + wn * 32 + nj * 16 + l16;
            float b = bias ? bias[col] : 0.f;
            int rbase = m0 + wm * 32 + mi * 16 + quad * 4;
            ushort_t* dstp = C;
            int c = col;
            if (C2 && col >= 256) { dstp = C2; c = col - 256; }
#pragma unroll
            for (int reg = 0; reg < 4; ++reg) {
                int r = rbase + reg;
                if (r >= M) continue;
                float v = acc[mi][nj][reg] + b;
                if (relu) v = fmaxf(v, 0.f);
                dstp[(size_t)r * 256 + c] = f2b(v);
            }
        }
    }
}

// ---------------- edge MLP: persistent waves, half-wave per edge, unroll 2, batched idx ------
// All __shfl here execute under full exec: j0 loop is wave-uniform, validity via ternaries.
__global__ __launch_bounds__(256) void k_edge(const ushort_t* __restrict__ P,
                                              const ushort_t* __restrict__ Q,
                                              const int2* __restrict__ csr,
                                              const int* __restrict__ row_start,
                                              const int* __restrict__ deg,
                                              const float* __restrict__ bm1,
                                              const float* __restrict__ Wm2,
                                              const float* __restrict__ bm2,
                                              float* __restrict__ out, int N, int stride) {
    int lane = threadIdx.x & 63;
    int wid = blockIdx.x * 4 + (threadIdx.x >> 6);
    int half = lane >> 5, l32 = lane & 31;

    // wave-lifetime constants: channels l32*8 .. +7
    float w0[8], w1[8], bb[8];
    const float* bp = bm1 + l32 * 8;
    const float2* wp = (const float2*)Wm2 + l32 * 8;
#pragma unroll
    for (int i = 0; i < 8; ++i) {
        float2 wv = wp[i];
        w0[i] = wv.x; w1[i] = wv.y;
        bb[i] = bp[i];
    }
    float bo0 = bm2[0], bo1 = bm2[1];

    for (int node = wid; node < N; node += stride) {
        int start = row_start[node];
        int cnt = deg[node];
        if (cnt == 0) continue;

        short8 qv = *(const short8*)(Q + (size_t)node * HID + l32 * 8);
        float qb[8];
#pragma unroll
        for (int i = 0; i < 8; ++i) qb[i] = b2f((ushort_t)qv[i]) + bb[i];

        const int2* sp = csr + start;
        for (int b = 0; b < cnt; b += 64) {
            int nb = min(64, cnt - b);
            int2 se = (lane < nb) ? sp[b + lane] : make_int2(0, 0);
            for (int j0 = 0; j0 < nb; j0 += 4) {
                int jA = j0 + half;
                int jB = j0 + 2 + half;
                bool vA = jA < nb, vB = jB < nb;
                int iA = vA ? jA : 0, iB = vB ? jB : 0;
                int sA = __shfl(se.x, iA, 64);
                int sB = __shfl(se.x, iB, 64);
                short8 pA = *(const short8*)(P + (size_t)sA * HID + l32 * 8);
                short8 pB = *(const short8*)(P + (size_t)sB * HID + l32 * 8);
                float aA0 = 0.f, aA1 = 0.f, aB0 = 0.f, aB1 = 0.f;
#pragma unroll
                for (int i = 0; i < 8; ++i) {
                    float hA = fmaxf(b2f((ushort_t)pA[i]) + qb[i], 0.f);
                    float hB = fmaxf(b2f((ushort_t)pB[i]) + qb[i], 0.f);
                    aA0 += hA * w0[i]; aA1 += hA * w1[i];
                    aB0 += hB * w0[i]; aB1 += hB * w1[i];
                }
#pragma unroll
                for (int off = 16; off > 0; off >>= 1) {
                    aA0 += __shfl_down(aA0, off, 32);
                    aA1 += __shfl_down(aA1, off, 32);
                    aB0 += __shfl_down(aB0, off, 32);
                    aB1 += __shfl_down(aB1, off, 32);
                }
                int eA = __shfl(se.y, iA, 64);
                int eB = __shfl(se.y, iB, 64);
                if (l32 == 0) {
                    if (vA) {
                        float2 o; o.x = aA0 + bo0; o.y = aA1 + bo1;
                        ((float2*)out)[eA] = o;
                    }
                    if (vB) {
                        float2 o; o.x = aB0 + bo0; o.y = aB1 + bo1;
                        ((float2*)out)[eB] = o;
                    }
                }
            }
        }
    }
}

extern "C" void kernel_launch(void* const* d_in, const int* in_sizes, int n_in,
                              void* d_out, int out_size, void* d_ws, size_t ws_size,
                              hipStream_t stream) {
    const float* x   = (const float*)d_in[0];
    const int*   ei  = (const int*)d_in[1];
    const float* W1l = (const float*)d_in[2];
    const float* b1l = (const float*)d_in[3];
    const float* W1r = (const float*)d_in[4];
    const float* W2l = (const float*)d_in[5];
    const float* b2l = (const float*)d_in[6];
    const float* W2r = (const float*)d_in[7];
    const float* Wm1 = (const float*)d_in[8];
    const float* bm1 = (const float*)d_in[9];
    const float* Wm2 = (const float*)d_in[10];
    const float* bm2 = (const float*)d_in[11];

    const int N = in_sizes[0] / IN_DIM;   // 50000
    const int E = in_sizes[1] / 2;        // 800000
    const int* src = ei;
    const int* dst = ei + E;
    const int NB = (N + SCAN_CHUNK - 1) / SCAN_CHUNK;

    // ---- workspace ----
    char* ws = (char*)d_ws;
    size_t off = 0;
    auto alloc = [&](size_t bytes) { void* p = ws + off; off = (off + bytes + 255) & ~(size_t)255; return p; };
    int* deg       = (int*)alloc((size_t)N * 4);
    int* row_start = (int*)alloc((size_t)N * 4);
    int* cursor    = (int*)alloc((size_t)N * 4);
    int* partials  = (int*)alloc((size_t)(NB + 1) * 4);
    int2* csr      = (int2*)alloc((size_t)E * 8);
    size_t matB = (size_t)N * HID * sizeof(ushort_t);          // 25.6 MB
    ushort_t* xb   = (ushort_t*)alloc(matB);
    ushort_t* aggB = (ushort_t*)alloc(matB);
    ushort_t* h1b  = (ushort_t*)alloc(matB);
    ushort_t* h2b  = (ushort_t*)alloc(matB);
    ushort_t* Pb   = (ushort_t*)alloc(matB);
    ushort_t* Qb   = (ushort_t*)alloc(matB);
    size_t wfB  = (size_t)8 * 16 * 2 * 512 * sizeof(ushort_t);  // 256 KB
    ushort_t* WF1l = (ushort_t*)alloc(wfB);
    ushort_t* WF1r = (ushort_t*)alloc(wfB);
    ushort_t* WF2l = (ushort_t*)alloc(wfB);
    ushort_t* WF2r = (ushort_t*)alloc(wfB);
    ushort_t* WFm  = (ushort_t*)alloc(wfB * 2);                 // nbTot=32
    float* out = (float*)d_out;

    int nwg = (N + 3) / 4;
    int mrows = (N + 63) / 64;

    // ---- CSR build ----
    hipMemsetAsync(deg, 0, (size_t)N * 4, stream);
    k_count_deg<<<(E + 255) / 256, 256, 0, stream>>>(dst, deg, E);
    k_chunk_sum<<<NB, 64, 0, stream>>>(deg, partials, N);
    k_scan_partials<<<1, 64, 0, stream>>>(partials, NB);
    k_scan_chunks<<<NB, 64, 0, stream>>>(deg, partials, row_start, cursor, N);
    k_bucket<<<(E + 255) / 256, 256, 0, stream>>>(src, dst, cursor, csr, E);

    // ---- casts / weight prep ----
    k_cast<<<(N * HID / 4 + 255) / 256, 256, 0, stream>>>(x, xb, N * HID / 4);
    k_wprep<<<128, 64, 0, stream>>>(W1l, WF1l, 16, 0);
    k_wprep<<<128, 64, 0, stream>>>(W1r, WF1r, 16, 0);
    k_wprep<<<128, 64, 0, stream>>>(W2l, WF2l, 16, 0);
    k_wprep<<<128, 64, 0, stream>>>(W2r, WF2r, 16, 0);
    k_wprep<<<128, 64, 0, stream>>>(Wm1, WFm, 32, 0);
    k_wprep<<<128, 64, 0, stream>>>(Wm1 + (size_t)256 * 256, WFm, 32, 16);

    // ---- conv1 ----
    k_gather<<<nwg, 256, 0, stream>>>(xb, csr, row_start, deg, aggB, N);
    k_mfma<<<dim3(4, mrows), 256, 0, stream>>>(aggB, WF1l, xb, WF1r, b1l, 1, N, 16, h1b, nullptr);

    // ---- conv2 ----
    k_gather<<<nwg, 256, 0, stream>>>(h1b, csr, row_start, deg, aggB, N);
    k_mfma<<<dim3(4, mrows), 256, 0, stream>>>(aggB, WF2l, h1b, WF2r, b2l, 1, N, 16, h2b, nullptr);

    // ---- P|Q fused GEMM -> Pb, Qb ----
    k_mfma<<<dim3(8, mrows), 256, 0, stream>>>(h2b, WFm, nullptr, nullptr, nullptr, 0, N, 32, Pb, Qb);

    // ---- edge MLP (persistent waves) ----
    const int EB = 2048;                  // 8 blocks/CU, 32 waves/CU
    k_edge<<<EB, 256, 0, stream>>>(Pb, Qb, csr, row_start, deg, bm1, Wm2, bm2, out, N, EB * 4);
}